// Round 3
// baseline (216.829 us; speedup 1.0000x reference)
//
#include <hip/hip_runtime.h>

// TrigHashGrid: B=1048576, IN_DIM=3, M=3, N=16, C=2, W=1000, A=-0.75
// Thread = (b, n). BLK=512 = 128 b's x 4 n's; blockIdx&3 picks which 4 of the
// 16 levels -> LDS stage = 4 levels x 1004 w x 2 c = 32128 B -> 4 blocks/CU
// = 32 waves/CU (VGPR ~52 allows 9 waves/EU; LDS was the limiter at 64KB).
// NOTE R2 (BLK=1024, launch_bounds(1024,8), 64KB LDS) passed first validation
// but diverged on graph replays; reverting to the R1-proven 512-thread config.
// LDS rows zero-padded 2 taps each side: OOR taps read 0.0 (== reference's
// valid mask); the 4 taps are CONSECUTIVE float2s (imm-offset ds_read_b64s).
// Output: wave writes 4 consecutive float2 per b = aligned 32B sectors.

constexpr int B_TOT = 1048576;
constexpr float A_C = -0.75f;

#define BLK 512
#define WPAD 1004            // 2 + 1000 + 2
#define RSTRIDE (WPAD * 2)   // 2008 floats per level row (w-major, c inner)
#define NLEV 4               // levels staged per block

// |a| <= ~100 here. Cody-Waite 2-term pi/2 reduction + cephes minimax polys:
// abs err ~2e-7, no libm slow-path VGPR bloat.
__device__ __forceinline__ float fast_sin(float x) {
    float kf = rintf(x * 0.63661977236758134f);            // x * 2/pi
    float r  = fmaf(-kf, 1.57079637f, x);                  // f32(pi/2), exact fma
    r        = fmaf(kf, 4.37113900e-8f, r);                // f32(pi/2) - pi/2
    int q = (int)kf;
    float r2 = r * r;
    float sp = fmaf(r2, fmaf(r2, -1.9515295891e-4f, 8.3321608736e-3f),
                    -1.6666654611e-1f);
    sp = fmaf(r * r2, sp, r);                              // sin(r)
    float cp = fmaf(r2, fmaf(r2, 2.4433157118e-5f, -1.3887316255e-3f),
                    4.1666645683e-2f);
    float c  = fmaf(r2 * r2, cp, fmaf(r2, -0.5f, 1.0f));   // cos(r)
    float res = (q & 1) ? c : sp;
    return (q & 2) ? -res : res;
}

__global__ __launch_bounds__(BLK, 4)
void trig_hashgrid(const float* __restrict__ x, const float* __restrict__ grids,
                   const float* __restrict__ G, const float* __restrict__ H,
                   float* __restrict__ out)
{
    __shared__ float lds[NLEV * RSTRIDE];     // 32128 B
    const int tid = threadIdx.x;
    const int grp = blockIdx.x & 3;           // which 4 of the 16 levels
    const int blk = blockIdx.x >> 2;          // 0..1023

    // Zero the 8 pad floats per level row (padded w {0,1,1002,1003} x c {0,1}).
    if (tid < NLEV * 8) {
        int nl = tid >> 3, j = tid & 7;
        int off = (j < 4) ? j : (RSTRIDE - 8 + j);
        lds[nl * RSTRIDE + off] = 0.0f;
    }
    // Stage grids[grp*4 .. grp*4+4) : global (n,c,w) -> LDS (n_loc, w+2, c).
    for (int i = tid; i < NLEV * 2000; i += BLK) {
        int n_loc = i / 2000;
        int rem   = i - n_loc * 2000;
        int c     = rem / 1000;
        int w     = rem - c * 1000;
        lds[n_loc * RSTRIDE + (w + 2) * 2 + c] = grids[grp * (NLEV * 2000) + i];
    }

    const int n_loc = tid & 3;
    const int n     = grp * 4 + n_loc;        // fixed per thread
    const int g     = tid >> 2;               // 0..127

    // Per-level frequencies/phases in registers (reused 8 iters).
    float G0[3], G1[3], G2[3], Hr[3];
#pragma unroll
    for (int m = 0; m < 3; ++m) {
        G0[m] = G[0 * 48 + m * 16 + n];
        G1[m] = G[1 * 48 + m * 16 + n];
        G2[m] = G[2 * 48 + m * 16 + n];
        Hr[m] = H[m * 16 + n];
    }
    __syncthreads();

    float2* __restrict__ out2 = (float2*)out;
    const float* lrow = &lds[n_loc * RSTRIDE];

    // 8 iterations: b stride = 1024 b-groups * 128 b's.
    for (int b = blk * 128 + g; b < B_TOT; b += 1024 * 128) {
        float x0 = x[b * 3 + 0];
        float x1 = x[b * 3 + 1];
        float x2 = x[b * 3 + 2];

        float p = 1.0f;
#pragma unroll
        for (int m = 0; m < 3; ++m) {
            float a = fmaf(x2, G2[m], fmaf(x1, G1[m], x0 * G0[m])) + Hr[m];
            p *= fast_sin(a);
        }

        float ix = fmaf(p + 1.0f, 500.0f, -0.5f);          // [-0.5, 999.5]
        float xf = floorf(ix);
        float t  = ix - xf;
        int base = (int)xf;                                // [-1, 999]
        base = min(max(base, -1), 999);                    // cheap insurance

        // Factored Keys weights:
        // w0 = A t u^2, w3 = A t^2 u, w1 = ((A+2)t-(A+3))t^2+1, w2 = 1-rest
        float u   = 1.0f - t;
        float tu  = t * u;
        float atu = A_C * tu;
        float w0  = atu * u;
        float w3  = atu * t;
        float w1  = fmaf(fmaf(A_C + 2.0f, t, -(A_C + 3.0f)), t * t, 1.0f);
        float w2  = 1.0f - w0 - w1 - w3;

        // 4 consecutive padded taps starting at padded index base+1 >= 0.
        const float* tap = lrow + (base + 1) * 2;
        float2 v0 = *(const float2*)(tap + 0);
        float2 v1 = *(const float2*)(tap + 2);
        float2 v2 = *(const float2*)(tap + 4);
        float2 v3 = *(const float2*)(tap + 6);

        float o0 = v0.x * w0, o1 = v0.y * w0;
        o0 = fmaf(v1.x, w1, o0); o1 = fmaf(v1.y, w1, o1);
        o0 = fmaf(v2.x, w2, o0); o1 = fmaf(v2.y, w2, o1);
        o0 = fmaf(v3.x, w3, o0); o1 = fmaf(v3.y, w3, o1);

        // out[b, n, c] flat = b*32 + n*2 + c -> float2 at b*16 + n
        out2[b * 16 + n] = make_float2(o0, o1);
    }
}

extern "C" void kernel_launch(void* const* d_in, const int* in_sizes, int n_in,
                              void* d_out, int out_size, void* d_ws, size_t ws_size,
                              hipStream_t stream) {
    const float* x     = (const float*)d_in[0];
    const float* grids = (const float*)d_in[1];
    const float* G     = (const float*)d_in[2];
    const float* H     = (const float*)d_in[3];
    float* out = (float*)d_out;
    trig_hashgrid<<<4096, BLK, 0, stream>>>(x, grids, G, H, out);
}

// Round 4
// 203.746 us; speedup vs baseline: 1.0642x; 1.0642x over previous
//
#include <hip/hip_runtime.h>

// TrigHashGrid: B=1048576, IN_DIM=3, M=3, N=16, C=2, W=1000, A=-0.75
// R4: R1 mapping (BLK=512 = 64 b x 8 n; blockIdx&1 picks 8-level half; 64KB
// LDS -> 2 blocks/CU) + padded zero rows + factored Keys weights + HARDWARE
// v_sin_f32 (sin(2pi*x): mul+fract+sin = 3 instrs vs ~18 for poly sin+cos).
// Error budget: rev-quantization ~6e-6 rad at |a|~100 == existing a-quant
// error that gave absmax 2e-3 -> predict ~4-6e-3 < 8.87e-3 threshold.
// Full 64B output lines per wave (8 n's contiguous per b). Strip-mined
// coalesced staging (no div/mod).

constexpr int B_TOT = 1048576;
constexpr float A_C = -0.75f;

#define BLK 512
#define WPAD 1004            // 2 + 1000 + 2
#define RSTRIDE (WPAD * 2)   // 2008 floats per level row (w-major, c inner)

__device__ __forceinline__ float hw_sin(float a) {
    // sin(a) = v_sin_f32(fract(a / 2pi)); v_fract wraps negatives correctly.
    float rev = a * 0.15915494309189535f;
    rev = __builtin_amdgcn_fractf(rev);
    return __builtin_amdgcn_sinf(rev);
}

__global__ __launch_bounds__(BLK, 4)
void trig_hashgrid(const float* __restrict__ x, const float* __restrict__ grids,
                   const float* __restrict__ G, const float* __restrict__ H,
                   float* __restrict__ out)
{
    __shared__ float lds[8 * RSTRIDE];        // 64256 B -> 2 blocks/CU
    const int tid  = threadIdx.x;
    const int half = blockIdx.x & 1;          // which 8 of the 16 levels
    const int blk  = blockIdx.x >> 1;         // 0..1023

    // Zero the 8 pad floats per level row (padded w {0,1,1002,1003} x c {0,1}).
    if (tid < 64) {
        int nl = tid >> 3, j = tid & 7;
        int off = (j < 4) ? j : (RSTRIDE - 8 + j);
        lds[nl * RSTRIDE + off] = 0.0f;
    }
    // Stage grids[half*8 .. half*8+8): strip per row; lanes read consecutive w
    // (coalesced 256B); LDS writes stride 8B (2-way, free on gfx950).
    {
        int row = tid >> 6;                   // 0..7 (level within half)
        int j   = tid & 63;
        const float* gsrc = grids + half * 16000 + row * 2000;
        float* ldst = lds + row * RSTRIDE;
#pragma unroll
        for (int c = 0; c < 2; ++c)
            for (int w = j; w < 1000; w += 64)
                ldst[(w + 2) * 2 + c] = gsrc[c * 1000 + w];
    }

    const int n_loc = tid & 7;
    const int n     = half * 8 + n_loc;       // fixed per thread
    const int g     = tid >> 3;               // 0..63

    // Per-level frequencies/phases in registers (reused 16 iters).
    float G0[3], G1[3], G2[3], Hr[3];
#pragma unroll
    for (int m = 0; m < 3; ++m) {
        G0[m] = G[0 * 48 + m * 16 + n];
        G1[m] = G[1 * 48 + m * 16 + n];
        G2[m] = G[2 * 48 + m * 16 + n];
        Hr[m] = H[m * 16 + n];
    }
    __syncthreads();

    float2* __restrict__ out2 = (float2*)out;
    const float* lrow = &lds[n_loc * RSTRIDE];

    // 16 iterations: b stride = 1024 b-groups * 64 b's.
#pragma unroll 2
    for (int b = blk * 64 + g; b < B_TOT; b += 1024 * 64) {
        float x0 = x[b * 3 + 0];
        float x1 = x[b * 3 + 1];
        float x2 = x[b * 3 + 2];

        float p = 1.0f;
#pragma unroll
        for (int m = 0; m < 3; ++m) {
            float a = fmaf(x0, G0[m], fmaf(x1, G1[m], fmaf(x2, G2[m], Hr[m])));
            p *= hw_sin(a);
        }

        float ix = fmaf(p, 500.0f, 499.5f);                // [-0.5, 999.5]
        float xf = floorf(ix);
        float t  = ix - xf;
        int base = (int)xf;                                // [-1, 999]
        base = min(max(base, -1), 999);                    // cheap insurance

        // Factored Keys weights:
        // w0 = A t u^2, w3 = A t^2 u, w1 = ((A+2)t-(A+3))t^2+1, w2 = 1-rest
        float u   = 1.0f - t;
        float tu  = t * u;
        float atu = A_C * tu;
        float w0  = atu * u;
        float w3  = atu * t;
        float w1  = fmaf(fmaf(A_C + 2.0f, t, -(A_C + 3.0f)), t * t, 1.0f);
        float w2  = 1.0f - w0 - w1 - w3;

        // 4 consecutive padded taps starting at padded index base+1 >= 0.
        const float* tap = lrow + (base + 1) * 2;
        float2 v0 = *(const float2*)(tap + 0);
        float2 v1 = *(const float2*)(tap + 2);
        float2 v2 = *(const float2*)(tap + 4);
        float2 v3 = *(const float2*)(tap + 6);

        float o0 = v0.x * w0, o1 = v0.y * w0;
        o0 = fmaf(v1.x, w1, o0); o1 = fmaf(v1.y, w1, o1);
        o0 = fmaf(v2.x, w2, o0); o1 = fmaf(v2.y, w2, o1);
        o0 = fmaf(v3.x, w3, o0); o1 = fmaf(v3.y, w3, o1);

        // out[b, n, c] flat = b*32 + n*2 + c -> float2 at b*16 + n
        // wave = 8 b x 8 n -> full 64B lines per b.
        out2[b * 16 + n] = make_float2(o0, o1);
    }
}

extern "C" void kernel_launch(void* const* d_in, const int* in_sizes, int n_in,
                              void* d_out, int out_size, void* d_ws, size_t ws_size,
                              hipStream_t stream) {
    const float* x     = (const float*)d_in[0];
    const float* grids = (const float*)d_in[1];
    const float* G     = (const float*)d_in[2];
    const float* H     = (const float*)d_in[3];
    float* out = (float*)d_out;
    trig_hashgrid<<<2048, BLK, 0, stream>>>(x, grids, G, H, out);
}